// Round 14
// baseline (266.025 us; speedup 1.0000x reference)
//
#include <hip/hip_runtime.h>
#include <hip/hip_bf16.h>

typedef signed char s8;
typedef unsigned int u32;
typedef unsigned long long u64;
typedef __attribute__((ext_vector_type(4))) int v4i;

#define M_TOK 16384        // 8 * 2048 tokens
#define DDIM 512
#define NCODES 8192
#define NTILE 64           // NCODES / 128 (col-tile count)
#define BKB 64             // K elems (=bytes) per tile at i8
#define KCH 8              // 512 / 64
#define NCAND 6            // recheck candidates

#define QS   25.4f         // 127/5  (clip at 5 sigma)
#define QINV (1.0f / (QS * QS))

// workspace layout (bytes)
#define OFF_A8   0u            //  8 MB  i8(x)
#define OFF_B8   8388608u      //  4 MB  i8(cb)
#define OFF_PART 12582912u     //  8 MB  u64 per (token, ntile)
#define OFF_C2   20971520u     // 32 KB
#define OFF_ACC  21004288u     //  4 B
#define OFF_CNT  21004292u     //  4 B

// ---------------- fused prep: zero + cb->i8 + c2 + x->i8 ------------------
__global__ void prep_kernel(const float* __restrict__ x, const float* __restrict__ cb,
                            s8* __restrict__ A8, s8* __restrict__ B8,
                            float* __restrict__ c2, float* __restrict__ acc,
                            u32* __restrict__ counter) {
    int bid = blockIdx.x;
    if (bid == 0 && threadIdx.x == 0) { *acc = 0.f; *counter = 0u; }
    if (bid < 2048) {
        // codebook: 4 rows per block, 1 row per wave
        int row = bid * 4 + (threadIdx.x >> 6);
        int l   = threadIdx.x & 63;
        const float* p = cb + (size_t)row * DDIM + l * 8;
        float4 a = *(const float4*)p;
        float4 b = *(const float4*)(p + 4);
        float v[8] = {a.x, a.y, a.z, a.w, b.x, b.y, b.z, b.w};
        union { s8 c[8]; uint2 q; } H;
        float s = 0.f;
        #pragma unroll
        for (int j = 0; j < 8; ++j) {
            int q = (int)rintf(fminf(fmaxf(v[j] * QS, -127.f), 127.f));
            H.c[j] = (s8)q;
            s += v[j] * v[j];
        }
        *(uint2*)(B8 + (size_t)row * DDIM + l * 8) = H.q;
        #pragma unroll
        for (int off = 32; off; off >>= 1) s += __shfl_down(s, off);
        if (l == 0) c2[row] = s;
    } else {
        // x: 16 elems per thread
        int i = (bid - 2048) * 256 + threadIdx.x;
        const float4* s4 = (const float4*)x + (size_t)i * 4;
        union { s8 c[16]; uint4 q; } H;
        #pragma unroll
        for (int k = 0; k < 4; ++k) {
            float4 a = s4[k];
            float v[4] = {a.x, a.y, a.z, a.w};
            #pragma unroll
            for (int j = 0; j < 4; ++j) {
                int q = (int)rintf(fminf(fmaxf(v[j] * QS, -127.f), 127.f));
                H.c[k * 4 + j] = (s8)q;
            }
        }
        *(uint4*)(A8 + (size_t)i * 16) = H.q;
    }
}

// ---- i8 MFMA GEMM: 256x128 block, 4 waves of 128x64 (af[8] x bf[4]) ------
// 85 ops/LDS-byte (vs 64 at 64x64 wave) -> MFMA-bound for the first time.
// Triple-buffer distance-2 prefetch (r13 discipline), 6 glds/stage.
// LDS: 3x(16K A + 8K B) + 4K merge = 76 KB -> 2 blocks/CU (= VGPR cap).
__launch_bounds__(256, 2)
__global__ void gemm_top1_kernel(const s8* __restrict__ A8, const s8* __restrict__ B8,
                                 const float* __restrict__ c2, u64* __restrict__ part) {
    __shared__ __align__(16) s8 Asb[3][256 * BKB];   // 3 x 16 KB
    __shared__ __align__(16) s8 Bsb[3][128 * BKB];   // 3 x 8 KB
    __shared__ u64 mergebuf[256][2];                 // 4 KB

    const int tid = threadIdx.x;
    const int wid = tid >> 6;
    const int l   = tid & 63;
    const int wr  = wid >> 1, wc = wid & 1;   // 2M x 2N waves
    const int mtile = blockIdx.x >> 6;        // 0..63
    const int ntile = blockIdx.x & 63;        // 0..63
    const int row0 = mtile * 256;
    const int col0 = ntile * 128;

    const int lg = l >> 4;                    // lane group 0..3
    const int lc = l & 15;

    // staging: per gld round, 64 rows x 64B; lane l -> row (l>>2), slot (l&3).
    // LDS[row][s] holds global k-slot s ^ ((row>>1)&3)  (r8/r10-verified).
    const int srowoff = l >> 2;
    const int sslot   = (l & 3) ^ ((l >> 3) & 3);   // pre-swizzled source slot

    // 6 global_load_lds per thread per STAGE (4 A rounds + 2 B rounds)
    auto STAGE = [&](int buf, int kc) {
        const int k0 = kc * BKB;
        #pragma unroll
        for (int i = 0; i < 4; ++i) {
            int rbase = i * 64 + wid * 16;
            int row = rbase + srowoff;
            const s8* ga = A8 + (size_t)(row0 + row) * DDIM + k0 + sslot * 16;
            __builtin_amdgcn_global_load_lds(
                (const __attribute__((address_space(1))) void*)ga,
                (__attribute__((address_space(3))) void*)&Asb[buf][rbase * BKB], 16, 0, 0);
        }
        #pragma unroll
        for (int i = 0; i < 2; ++i) {
            int rbase = i * 64 + wid * 16;
            int row = rbase + srowoff;
            const s8* gb = B8 + (size_t)(col0 + row) * DDIM + k0 + sslot * 16;
            __builtin_amdgcn_global_load_lds(
                (const __attribute__((address_space(1))) void*)gb,
                (__attribute__((address_space(3))) void*)&Bsb[buf][rbase * BKB], 16, 0, 0);
        }
    };

    v4i acc[8][4];
    #pragma unroll
    for (int m = 0; m < 8; ++m)
        #pragma unroll
        for (int n = 0; n < 4; ++n) acc[m][n] = (v4i){0, 0, 0, 0};

    // prologue: stages for tiles 0,1 in flight (12 glds)
    STAGE(0, 0);
    STAGE(1, 1);

    const int slotbyte = (lg ^ ((lc >> 1) & 3)) * 16;   // read swizzle (r8/r10-verified)

    #pragma unroll
    for (int kc = 0; kc < KCH; ++kc) {
        const int buf = kc % 3;
        // RACE DISCIPLINE (r8-proven): my ds_reads of the buffer the next STAGE
        // will overwrite must COMPLETE before I release B1.
        asm volatile("s_waitcnt lgkmcnt(0)" ::: "memory");
        __builtin_amdgcn_sched_barrier(0);
        asm volatile("s_barrier" ::: "memory");          // B1
        if (kc < KCH - 2) STAGE((kc + 2) % 3, kc + 2);
        // tile kc landed when <= (stages kc+1, kc+2) = 12 outstanding (in-order)
        if (kc < KCH - 2) {
            asm volatile("s_waitcnt vmcnt(12)" ::: "memory");
        } else if (kc == KCH - 2) {
            asm volatile("s_waitcnt vmcnt(6)" ::: "memory");
        } else {
            asm volatile("s_waitcnt vmcnt(0)" ::: "memory");
        }
        asm volatile("s_barrier" ::: "memory");          // B2

        v4i af[8], bf[4];
        #pragma unroll
        for (int m = 0; m < 8; ++m) {
            int row = wr * 128 + m * 16 + lc;
            af[m] = *(const v4i*)((const char*)&Asb[buf][0] + row * BKB + slotbyte);
        }
        #pragma unroll
        for (int n = 0; n < 4; ++n) {
            int row = wc * 64 + n * 16 + lc;
            bf[n] = *(const v4i*)((const char*)&Bsb[buf][0] + row * BKB + slotbyte);
        }
        __builtin_amdgcn_s_setprio(1);
        #pragma unroll
        for (int m = 0; m < 8; ++m)
            #pragma unroll
            for (int n = 0; n < 4; ++n)
                acc[m][n] = __builtin_amdgcn_mfma_i32_16x16x64_i8(af[m], bf[n], acc[m][n], 0, 0, 0);
        __builtin_amdgcn_s_setprio(0);
    }

    // ---- epilogue: per-row min over this block's 128 columns, packed u64 ----
    // D layout: col = lc, row = lg*4 + j (dtype-independent; verified r3-r13)
    float c2v[4];
    #pragma unroll
    for (int n = 0; n < 4; ++n) c2v[n] = c2[col0 + wc * 64 + n * 16 + lc];

    #pragma unroll
    for (int m = 0; m < 8; ++m) {
        #pragma unroll
        for (int j = 0; j < 4; ++j) {
            int rloc = wr * 128 + m * 16 + lg * 4 + j;
            u64 best = ~0ull;
            #pragma unroll
            for (int n = 0; n < 4; ++n) {
                float s = c2v[n] - 2.0f * (float)acc[m][n][j] * QINV;
                u32 b = __float_as_uint(s);
                b = (b & 0x80000000u) ? ~b : (b | 0x80000000u);   // monotone float->u32
                int col = col0 + wc * 64 + n * 16 + lc;
                u64 key = ((u64)b << 32) | (u32)col;              // low bits: index tie-break
                best = key < best ? key : best;
            }
            #pragma unroll
            for (int off = 1; off < 16; off <<= 1) {
                u64 o = __shfl_xor(best, off);
                best = o < best ? o : best;
            }
            if (lc == 0) mergebuf[rloc][wc] = best;
        }
    }
    __syncthreads();   // full drain before cross-wave merge read
    {
        u64 a = mergebuf[tid][0], b = mergebuf[tid][1];
        part[(size_t)(row0 + tid) * NTILE + ntile] = a < b ? a : b;
    }
}

// ---- merge 64 winners -> top-6, streamed fp64 recheck, quantize + idx +
// ---- loss. Finalize via atomics + vmcnt ordering (no __threadfence).
__launch_bounds__(256)
__global__ void reduce_quant_kernel(const u64* __restrict__ part,
                                    const float* __restrict__ x, const float* __restrict__ cb,
                                    float* __restrict__ out, float* __restrict__ acc,
                                    u32* __restrict__ counter) {
    __shared__ float red[4];
    int t = blockIdx.x * 4 + (threadIdx.x >> 6);
    int l = threadIdx.x & 63;
    u64 k = part[(size_t)t * NTILE + l];

    int cand[NCAND];
    #pragma unroll
    for (int c = 0; c < NCAND; ++c) {
        u64 m = k;
        #pragma unroll
        for (int off = 1; off < 64; off <<= 1) {
            u64 o = __shfl_xor(m, off);
            m = o < m ? o : m;
        }
        cand[c] = (int)(u32)(m & 0xffffffffull);
        if (k == m) k = ~0ull;        // keys unique (distinct cols) -> removes one lane
    }

    const float* xp = x + (size_t)t * DDIM + l * 8;
    float xv[8];
    #pragma unroll
    for (int j = 0; j < 8; ++j) xv[j] = xp[j];

    // streamed: per-candidate row is transient; only d[c] stays live
    double d[NCAND];
    #pragma unroll
    for (int c = 0; c < NCAND; ++c) {
        const float* cpp = cb + (size_t)cand[c] * DDIM + l * 8;
        float4 r0 = *(const float4*)cpp;
        float4 r1 = *(const float4*)(cpp + 4);
        float cr[8] = {r0.x, r0.y, r0.z, r0.w, r1.x, r1.y, r1.z, r1.w};
        double s = 0.0;
        #pragma unroll
        for (int j = 0; j < 8; ++j) {
            double a = (double)cr[j] - (double)xv[j];
            s += a * a;
        }
        d[c] = s;
    }
    #pragma unroll
    for (int c = 0; c < NCAND; ++c) {
        #pragma unroll
        for (int off = 1; off < 64; off <<= 1) d[c] += __shfl_xor(d[c], off);
    }

    double bd = d[0]; int bi = cand[0];
    #pragma unroll
    for (int c = 1; c < NCAND; ++c)
        if (d[c] < bd || (d[c] == bd && cand[c] < bi)) { bd = d[c]; bi = cand[c]; }

    // reload ONLY the winning code row (L2/L3-resident, one 2KB gather/token)
    const float* cwp = cb + (size_t)bi * DDIM + l * 8;
    float4 w0 = *(const float4*)cwp;
    float4 w1 = *(const float4*)(cwp + 4);
    float cw[8] = {w0.x, w0.y, w0.z, w0.w, w1.x, w1.y, w1.z, w1.w};

    // quantized out = x + (codes - x); loss partial = sum diff^2
    float ls = 0.f;
    float4 o0, o1;
    float dj[8];
    #pragma unroll
    for (int j = 0; j < 8; ++j) { dj[j] = cw[j] - xv[j]; ls += dj[j] * dj[j]; }
    o0.x = xv[0] + dj[0]; o0.y = xv[1] + dj[1]; o0.z = xv[2] + dj[2]; o0.w = xv[3] + dj[3];
    o1.x = xv[4] + dj[4]; o1.y = xv[5] + dj[5]; o1.z = xv[6] + dj[6]; o1.w = xv[7] + dj[7];
    float* op = out + (size_t)t * DDIM + l * 8;
    *(float4*)op = o0;
    *(float4*)(op + 4) = o1;

    if (l == 0) out[(size_t)M_TOK * DDIM + t] = (float)bi;   // index as fp32

    #pragma unroll
    for (int off = 32; off; off >>= 1) ls += __shfl_down(ls, off);
    int wv = threadIdx.x >> 6;
    if (l == 0) red[wv] = ls;
    __syncthreads();
    if (threadIdx.x == 0) {
        // device-scope atomics operate at the coherent point (m20); order the
        // two RMWs with a plain vmcnt wait instead of a cache-flushing fence.
        atomicAdd(acc, red[0] + red[1] + red[2] + red[3]);
        asm volatile("s_waitcnt vmcnt(0)" ::: "memory");   // acc-RMW retired
        u32 old = atomicAdd(counter, 1u);
        if (old == gridDim.x - 1) {            // last block: all acc adds committed
            float total = atomicAdd(acc, 0.0f);   // atomic read at coherent point
            float mean = total / (float)((size_t)M_TOK * DDIM);
            out[(size_t)M_TOK * DDIM + M_TOK] = 2.0f * mean;
        }
    }
}

extern "C" void kernel_launch(void* const* d_in, const int* in_sizes, int n_in,
                              void* d_out, int out_size, void* d_ws, size_t ws_size,
                              hipStream_t stream) {
    const float* x  = (const float*)d_in[0];
    const float* cb = (const float*)d_in[1];
    float* out = (float*)d_out;
    char* ws = (char*)d_ws;

    s8*    A8   = (s8*)(ws + OFF_A8);
    s8*    B8   = (s8*)(ws + OFF_B8);
    u64*   part = (u64*)(ws + OFF_PART);
    float* c2   = (float*)(ws + OFF_C2);
    float* acc  = (float*)(ws + OFF_ACC);
    u32*   cnt  = (u32*)(ws + OFF_CNT);

    prep_kernel<<<4096, 256, 0, stream>>>(x, cb, A8, B8, c2, acc, cnt);
    gemm_top1_kernel<<<(M_TOK / 256) * (NCODES / 128), 256, 0, stream>>>(A8, B8, c2, part);
    reduce_quant_kernel<<<M_TOK / 4, 256, 0, stream>>>(part, x, cb, out, acc, cnt);
}

// Round 16
// 193.130 us; speedup vs baseline: 1.3774x; 1.3774x over previous
//
#include <hip/hip_runtime.h>
#include <hip/hip_bf16.h>

typedef signed char s8;
typedef unsigned int u32;
typedef unsigned long long u64;
typedef __attribute__((ext_vector_type(4))) int v4i;

#define M_TOK 16384        // 8 * 2048 tokens
#define DDIM 512
#define NCODES 8192
#define NTILE 64           // NCODES / 128
#define BKB 64             // K elems (=bytes) per tile at i8
#define KCH 8              // 512 / 64
#define NCAND 4            // recheck candidates (r10-proven quality)

#define QS   25.4f         // 127/5  (clip at 5 sigma)
#define QINV (1.0f / (QS * QS))

// workspace layout (bytes)
#define OFF_A8   0u            //  8 MB  i8(x)
#define OFF_B8   8388608u      //  4 MB  i8(cb)
#define OFF_PART 12582912u     //  8 MB  u64 per (token, ntile)
#define OFF_C2   20971520u     // 32 KB  float c2
#define OFF_ACC  21004288u     //  4 B

// ---------------- fused prep: zero + cb->i8 + c2 + x->i8 ------------------
__global__ void prep_kernel(const float* __restrict__ x, const float* __restrict__ cb,
                            s8* __restrict__ A8, s8* __restrict__ B8,
                            float* __restrict__ c2, float* __restrict__ acc) {
    int bid = blockIdx.x;
    if (bid == 0 && threadIdx.x == 0) { *acc = 0.f; }
    if (bid < 2048) {
        // codebook: 4 rows per block, 1 row per wave
        int row = bid * 4 + (threadIdx.x >> 6);
        int l   = threadIdx.x & 63;
        const float* p = cb + (size_t)row * DDIM + l * 8;
        float4 a = *(const float4*)p;
        float4 b = *(const float4*)(p + 4);
        float v[8] = {a.x, a.y, a.z, a.w, b.x, b.y, b.z, b.w};
        union { s8 c[8]; uint2 q; } H;
        float s = 0.f;
        #pragma unroll
        for (int j = 0; j < 8; ++j) {
            int q = (int)rintf(fminf(fmaxf(v[j] * QS, -127.f), 127.f));
            H.c[j] = (s8)q;
            s += v[j] * v[j];
        }
        *(uint2*)(B8 + (size_t)row * DDIM + l * 8) = H.q;
        #pragma unroll
        for (int off = 32; off; off >>= 1) s += __shfl_down(s, off);
        if (l == 0) c2[row] = s;
    } else {
        // x: 16 elems per thread
        int i = (bid - 2048) * 256 + threadIdx.x;
        const float4* s4 = (const float4*)x + (size_t)i * 4;
        union { s8 c[16]; uint4 q; } H;
        #pragma unroll
        for (int k = 0; k < 4; ++k) {
            float4 a = s4[k];
            float v[4] = {a.x, a.y, a.z, a.w};
            #pragma unroll
            for (int j = 0; j < 4; ++j) {
                int q = (int)rintf(fminf(fmaxf(v[j] * QS, -127.f), 127.f));
                H.c[k * 4 + j] = (s8)q;
            }
        }
        *(uint4*)(A8 + (size_t)i * 16) = H.q;
    }
}

// ---------------- i8 MFMA GEMM (r10 verbatim: 133 us measured) ------------
// S[m][n] = q(x[m]).q(c[n]) exact int32; score = c2[n] - 2 S/QS^2.
// Block: 128x128, 4 waves. LDS: 2 x (8KB A + 8KB B) + 2KB merge = 34 KB -> 4 blocks/CU.
__launch_bounds__(256, 4)
__global__ void gemm_top1_kernel(const s8* __restrict__ A8, const s8* __restrict__ B8,
                                 const float* __restrict__ c2, u64* __restrict__ part) {
    __shared__ __align__(16) s8 Asb[2][128 * BKB];   // 2 x 8 KB
    __shared__ __align__(16) s8 Bsb[2][128 * BKB];   // 2 x 8 KB
    __shared__ u64 mergebuf[128][2];

    const int tid = threadIdx.x;
    const int wid = tid >> 6;
    const int l   = tid & 63;
    const int wr  = wid >> 1, wc = wid & 1;
    const int mtile = blockIdx.x >> 6;      // 0..127
    const int ntile = blockIdx.x & 63;      // 0..63
    const int row0 = mtile * 128;
    const int col0 = ntile * 128;

    const int lg = l >> 4;                  // lane group 0..3
    const int lc = l & 15;

    // staging: per gld, 16 rows x 64B; lane l -> row (l>>2), dest slot (l&3).
    // LDS[row][s] holds global k-slot s ^ ((row>>1)&3)  (r8/r10-verified).
    const int srowoff = l >> 2;
    const int sslot   = (l & 3) ^ ((l >> 3) & 3);   // pre-swizzled source slot

    // 4 global_load_lds per thread per STAGE (2 A + 2 B)
    auto STAGE = [&](int buf, int kc) {
        const int k0 = kc * BKB;
        #pragma unroll
        for (int i = 0; i < 2; ++i) {
            int rbase = i * 64 + wid * 16;
            int row = rbase + srowoff;
            const s8* ga = A8 + (size_t)(row0 + row) * DDIM + k0 + sslot * 16;
            __builtin_amdgcn_global_load_lds(
                (const __attribute__((address_space(1))) void*)ga,
                (__attribute__((address_space(3))) void*)&Asb[buf][rbase * BKB], 16, 0, 0);
            const s8* gb = B8 + (size_t)(col0 + row) * DDIM + k0 + sslot * 16;
            __builtin_amdgcn_global_load_lds(
                (const __attribute__((address_space(1))) void*)gb,
                (__attribute__((address_space(3))) void*)&Bsb[buf][rbase * BKB], 16, 0, 0);
        }
    };

    v4i acc[4][4];
    #pragma unroll
    for (int m = 0; m < 4; ++m)
        #pragma unroll
        for (int n = 0; n < 4; ++n) acc[m][n] = (v4i){0, 0, 0, 0};

    STAGE(0, 0);
    int cur = 0;
    const int slotbyte = (lg ^ ((lc >> 1) & 3)) * 16;   // read swizzle (r8/r10-verified)
    for (int kc = 0; kc < KCH; ++kc) {
        // RACE DISCIPLINE (r8-proven): my ds_reads of buf[cur^1] must COMPLETE
        // before I release B1 (which authorizes overwriting that buffer).
        asm volatile("s_waitcnt lgkmcnt(0)" ::: "memory");
        __builtin_amdgcn_sched_barrier(0);
        asm volatile("s_barrier" ::: "memory");          // B1
        if (kc < KCH - 1) {
            STAGE(cur ^ 1, kc + 1);
            asm volatile("s_waitcnt vmcnt(4)" ::: "memory");  // prev stage only
        } else {
            asm volatile("s_waitcnt vmcnt(0)" ::: "memory");
        }
        asm volatile("s_barrier" ::: "memory");          // B2

        v4i af[4], bf[4];
        #pragma unroll
        for (int m = 0; m < 4; ++m) {
            int row = wr * 64 + m * 16 + lc;
            af[m] = *(const v4i*)((const char*)&Asb[cur][0] + row * BKB + slotbyte);
        }
        #pragma unroll
        for (int n = 0; n < 4; ++n) {
            int row = wc * 64 + n * 16 + lc;
            bf[n] = *(const v4i*)((const char*)&Bsb[cur][0] + row * BKB + slotbyte);
        }
        #pragma unroll
        for (int m = 0; m < 4; ++m)
            #pragma unroll
            for (int n = 0; n < 4; ++n)
                acc[m][n] = __builtin_amdgcn_mfma_i32_16x16x64_i8(af[m], bf[n], acc[m][n], 0, 0, 0);
        cur ^= 1;
    }

    // ---- epilogue: per-row min over this block's 128 columns, packed u64 ----
    // D layout: col = lc, row = lg*4 + j (dtype-independent; verified r3-r13)
    float c2v[4];
    #pragma unroll
    for (int n = 0; n < 4; ++n) c2v[n] = c2[col0 + wc * 64 + n * 16 + lc];

    #pragma unroll
    for (int m = 0; m < 4; ++m) {
        #pragma unroll
        for (int j = 0; j < 4; ++j) {
            int rloc = wr * 64 + m * 16 + lg * 4 + j;
            u64 best = ~0ull;
            #pragma unroll
            for (int n = 0; n < 4; ++n) {
                float s = c2v[n] - 2.0f * (float)acc[m][n][j] * QINV;
                u32 b = __float_as_uint(s);
                b = (b & 0x80000000u) ? ~b : (b | 0x80000000u);   // monotone float->u32
                int col = col0 + wc * 64 + n * 16 + lc;
                u64 key = ((u64)b << 32) | (u32)col;              // low bits: index tie-break
                best = key < best ? key : best;
            }
            #pragma unroll
            for (int off = 1; off < 16; off <<= 1) {
                u64 o = __shfl_xor(best, off);
                best = o < best ? o : best;
            }
            if (lc == 0) mergebuf[rloc][wc] = best;
        }
    }
    __syncthreads();   // full drain before cross-wave merge read
    if (tid < 128) {
        u64 a = mergebuf[tid][0], b = mergebuf[tid][1];
        part[(size_t)(row0 + tid) * NTILE + ntile] = a < b ? a : b;
    }
}

// ---- merge 64 winners -> top-4, streamed fp64 recheck, quantize + idx +
// ---- loss partials (plain device atomicAdd, r10-proven; no counter/fence).
__launch_bounds__(256)
__global__ void reduce_quant_kernel(const u64* __restrict__ part,
                                    const float* __restrict__ x, const float* __restrict__ cb,
                                    float* __restrict__ out, float* __restrict__ acc) {
    __shared__ float red[4];
    int t = blockIdx.x * 4 + (threadIdx.x >> 6);
    int l = threadIdx.x & 63;
    u64 k = part[(size_t)t * NTILE + l];

    int cand[NCAND];
    #pragma unroll
    for (int c = 0; c < NCAND; ++c) {
        u64 m = k;
        #pragma unroll
        for (int off = 1; off < 64; off <<= 1) {
            u64 o = __shfl_xor(m, off);
            m = o < m ? o : m;
        }
        cand[c] = (int)(u32)(m & 0xffffffffull);
        if (k == m) k = ~0ull;        // keys unique (distinct cols) -> removes one lane
    }

    const float* xp = x + (size_t)t * DDIM + l * 8;
    float xv[8];
    #pragma unroll
    for (int j = 0; j < 8; ++j) xv[j] = xp[j];

    // streamed: per-candidate row is transient; only d[c] stays live (no spill)
    double d[NCAND];
    #pragma unroll
    for (int c = 0; c < NCAND; ++c) {
        const float* cpp = cb + (size_t)cand[c] * DDIM + l * 8;
        float4 r0 = *(const float4*)cpp;
        float4 r1 = *(const float4*)(cpp + 4);
        float cr[8] = {r0.x, r0.y, r0.z, r0.w, r1.x, r1.y, r1.z, r1.w};
        double s = 0.0;
        #pragma unroll
        for (int j = 0; j < 8; ++j) {
            double a = (double)cr[j] - (double)xv[j];
            s += a * a;
        }
        d[c] = s;
    }
    #pragma unroll
    for (int c = 0; c < NCAND; ++c) {
        #pragma unroll
        for (int off = 1; off < 64; off <<= 1) d[c] += __shfl_xor(d[c], off);
    }

    double bd = d[0]; int bi = cand[0];
    #pragma unroll
    for (int c = 1; c < NCAND; ++c)
        if (d[c] < bd || (d[c] == bd && cand[c] < bi)) { bd = d[c]; bi = cand[c]; }

    // reload ONLY the winning code row (L2/L3-resident gather)
    const float* cwp = cb + (size_t)bi * DDIM + l * 8;
    float4 w0 = *(const float4*)cwp;
    float4 w1 = *(const float4*)(cwp + 4);
    float cw[8] = {w0.x, w0.y, w0.z, w0.w, w1.x, w1.y, w1.z, w1.w};

    // quantized out = x + (codes - x); loss partial = sum diff^2
    float ls = 0.f;
    float4 o0, o1;
    float dj[8];
    #pragma unroll
    for (int j = 0; j < 8; ++j) { dj[j] = cw[j] - xv[j]; ls += dj[j] * dj[j]; }
    o0.x = xv[0] + dj[0]; o0.y = xv[1] + dj[1]; o0.z = xv[2] + dj[2]; o0.w = xv[3] + dj[3];
    o1.x = xv[4] + dj[4]; o1.y = xv[5] + dj[5]; o1.z = xv[6] + dj[6]; o1.w = xv[7] + dj[7];
    float* op = out + (size_t)t * DDIM + l * 8;
    *(float4*)op = o0;
    *(float4*)(op + 4) = o1;

    if (l == 0) out[(size_t)M_TOK * DDIM + t] = (float)bi;   // index as fp32

    #pragma unroll
    for (int off = 32; off; off >>= 1) ls += __shfl_down(ls, off);
    int wv = threadIdx.x >> 6;
    if (l == 0) red[wv] = ls;
    __syncthreads();
    if (threadIdx.x == 0) atomicAdd(acc, red[0] + red[1] + red[2] + red[3]);
}

// ---------------- tiny separate finalize (r10-proven pattern) -------------
__global__ void loss_final_kernel(const float* __restrict__ acc, float* __restrict__ out) {
    if (threadIdx.x == 0 && blockIdx.x == 0) {
        float mean = (*acc) / (float)((size_t)M_TOK * DDIM);
        out[(size_t)M_TOK * DDIM + M_TOK] = 2.0f * mean;
    }
}

extern "C" void kernel_launch(void* const* d_in, const int* in_sizes, int n_in,
                              void* d_out, int out_size, void* d_ws, size_t ws_size,
                              hipStream_t stream) {
    const float* x  = (const float*)d_in[0];
    const float* cb = (const float*)d_in[1];
    float* out = (float*)d_out;
    char* ws = (char*)d_ws;

    s8*    A8   = (s8*)(ws + OFF_A8);
    s8*    B8   = (s8*)(ws + OFF_B8);
    u64*   part = (u64*)(ws + OFF_PART);
    float* c2   = (float*)(ws + OFF_C2);
    float* acc  = (float*)(ws + OFF_ACC);

    prep_kernel<<<4096, 256, 0, stream>>>(x, cb, A8, B8, c2, acc);
    gemm_top1_kernel<<<(M_TOK / 128) * NTILE, 256, 0, stream>>>(A8, B8, c2, part);
    reduce_quant_kernel<<<M_TOK / 4, 256, 0, stream>>>(part, x, cb, out, acc);
    loss_final_kernel<<<1, 64, 0, stream>>>(acc, out);
}